// Round 12
// baseline (72.306 us; speedup 1.0000x reference)
//
#include <hip/hip_runtime.h>
#include <cstdint>
#include <cstddef>

// HardDetectionModule: per-element detect = is_depth_wise_max & is_local_max & is_not_edge
// batch: (B=2, C=512, H=192, W=256) float32, row-major.
// Output: same shape, int32 0/1 (reference returns bool -> harness reads int32).
//
// R11 post-mortem: R6's zero-store-then-overwrite raced (NT store bypass path
// vs normal store L2 path to the SAME address; vmcnt(0) ack points differ ->
// intermittent post-timing divergence). R12: single store per element.
//   pass 1: loads only -> per-group "equals running max" masks (LDS)
//   pass 2: evaluate sparse candidates -> 4 named detect bitmasks (registers)
//   pass 3: stream final 0/1 values, one NT 8B store per column pair
// No address written twice -> deterministic by construction.

namespace {

constexpr int Bn = 2;
constexpr int Cn = 512;
constexpr int Hn = 192;
constexpr int Wn = 256;
constexpr int CH  = Hn * Wn;         // channel stride in elements (49152)
constexpr int SEG = 8;               // wave-segments per column
constexpr int CPS = Cn / SEG;        // 64 channels per segment
constexpr int GPS = CPS / 32;        // 2 mask-groups per segment
constexpr int NGROUPS = SEG * GPS;   // 16 total

__global__ __launch_bounds__(512)
void hard_detect_kernel(const float* __restrict__ in, int* __restrict__ out) {
    const int tid = threadIdx.x & 63;            // lane 0..63
    const int s   = threadIdx.x >> 6;            // segment (wave) 0..7
    const int j0  = blockIdx.x * 128 + tid * 2;  // even column of this lane's pair
    const int i   = blockIdx.y;                  // 0..191
    const int b   = blockIdx.z;                  // 0..1

    // [group][lane], 8B per lane -> 2-way LDS bank aliasing (free, m136).
    __shared__ uint2  smask[NGROUPS][64];
    __shared__ float2 smaxv[NGROUPS][64];

    // element index of (b, c=0, i, j0)
    const size_t base = ((size_t)b * Cn * Hn + (size_t)i) * Wn + (size_t)j0;

    // ---- Pass 1 (loads only): each wave streams its 64-channel segment of
    // 2 columns/lane, building per-32-channel-group bitmasks of
    // "v == running max" (mask resets when a strictly larger value appears)
    // plus the running max at group end. A group is valid iff its recorded
    // max equals the final column max; surviving bits then mark exactly the
    // channels equal to the column max (ties exact).
    float M0 = -__builtin_inff(), M1 = -__builtin_inff();
    for (int g = 0; g < GPS; ++g) {
        uint32_t m0 = 0u, m1 = 0u;
        #pragma unroll
        for (int k = 0; k < 32; ++k) {
            const int c = s * CPS + g * 32 + k;
            const size_t idx = base + (size_t)c * (size_t)CH;
            const float2 v = *reinterpret_cast<const float2*>(&in[idx]);
            if (v.x > M0) { M0 = v.x; m0 = (1u << k); }
            else if (v.x == M0) { m0 |= (1u << k); }
            if (v.y > M1) { M1 = v.y; m1 = (1u << k); }
            else if (v.y == M1) { m1 |= (1u << k); }
        }
        smask[s * GPS + g][tid] = make_uint2(m0, m1);
        smaxv[s * GPS + g][tid] = make_float2(M0, M1);
    }

    __syncthreads();

    // Global column maxes = max over the 8 segment-end running maxes.
    float Mg0 = smaxv[GPS - 1][tid].x;
    float Mg1 = smaxv[GPS - 1][tid].y;
    #pragma unroll
    for (int ss = 1; ss < SEG; ++ss) {
        Mg0 = fmaxf(Mg0, smaxv[ss * GPS + GPS - 1][tid].x);
        Mg1 = fmaxf(Mg1, smaxv[ss * GPS + GPS - 1][tid].y);
    }

    // ---- Pass 2: evaluate sparse candidates in this thread's segment into
    // detect bitmasks (no stores). det[col][g], fully unrolled -> static idx.
    uint32_t det[2][GPS];
    #pragma unroll
    for (int col = 0; col < 2; ++col)
        #pragma unroll
        for (int g = 0; g < GPS; ++g)
            det[col][g] = 0u;

    const bool has_u = (i > 0), has_d = (i < Hn - 1);

    #pragma unroll
    for (int col = 0; col < 2; ++col) {
        const int j = j0 + col;
        const float Mg = col ? Mg1 : Mg0;
        const bool has_l = (j > 0), has_r = (j < Wn - 1);

        #pragma unroll
        for (int g = 0; g < GPS; ++g) {
            const float2 sm = smaxv[s * GPS + g][tid];
            if ((col ? sm.y : sm.x) != Mg) continue;     // stale group
            const uint2 mm = smask[s * GPS + g][tid];
            uint32_t m = col ? mm.y : mm.x;
            while (m) {
                const int k = __ffs(m) - 1;
                m &= (m - 1u);
                const int c = s * CPS + g * 32 + k;
                const size_t p = base + (size_t)col + (size_t)c * (size_t)CH;
                const float v = Mg;                   // == in[p] by construction

                // 3x3 neighborhood; OOB -> 0 for the Hessian (zero-pad), and
                // the local-max test skips OOB neighbors (-inf pad semantics).
                const float nu  = has_u ? in[p - Wn] : 0.0f;
                const float nd  = has_d ? in[p + Wn] : 0.0f;
                const float nl  = has_l ? in[p - 1]  : 0.0f;
                const float nr  = has_r ? in[p + 1]  : 0.0f;
                const float nul = (has_u && has_l) ? in[p - Wn - 1] : 0.0f;
                const float nur = (has_u && has_r) ? in[p - Wn + 1] : 0.0f;
                const float ndl = (has_d && has_l) ? in[p + Wn - 1] : 0.0f;
                const float ndr = (has_d && has_r) ? in[p + Wn + 1] : 0.0f;

                const bool lm =
                    (!has_u || v >= nu) && (!has_d || v >= nd) &&
                    (!has_l || v >= nl) && (!has_r || v >= nr) &&
                    (!(has_u && has_l) || v >= nul) &&
                    (!(has_u && has_r) || v >= nur) &&
                    (!(has_d && has_l) || v >= ndl) &&
                    (!(has_d && has_r) || v >= ndr);

                if (lm) {
                    // Hessian edge test, f32 ops matching numpy rounding.
                    // __fmul_rn blocks fma contraction (det sign / ratio must
                    // round exactly like separate-mul-then-sub).
                    const float dii = (nu + nd) - 2.0f * v;
                    const float djj = (nl + nr) - 2.0f * v;
                    const float dij = 0.25f * (((nul - nur) - ndl) + ndr);
                    const float dt  = __fmul_rn(dii, djj) - __fmul_rn(dij, dij);
                    const float tr  = dii + djj;
                    const float ratio = __fmul_rn(tr, tr) / dt; // inf/nan ok if dt<=0
                    if (dt > 0.0f && ratio <= 7.2f) {           // 36/5
                        det[col][g] |= (1u << k);
                    }
                }
            }
        }
    }

    // ---- Pass 3: single NT 8B store per (channel, column-pair) with the
    // final 0/1 values. Every output element written exactly once.
    #pragma unroll
    for (int g = 0; g < GPS; ++g) {
        const uint32_t d0 = det[0][g], d1 = det[1][g];
        #pragma unroll
        for (int k = 0; k < 32; ++k) {
            const int c = s * CPS + g * 32 + k;
            const size_t idx = base + (size_t)c * (size_t)CH;
            const unsigned long long val =
                (unsigned long long)((d0 >> k) & 1u) |
                ((unsigned long long)((d1 >> k) & 1u) << 32);
            __builtin_nontemporal_store(val,
                reinterpret_cast<unsigned long long*>(&out[idx]));
        }
    }
}

} // namespace

extern "C" void kernel_launch(void* const* d_in, const int* in_sizes, int n_in,
                              void* d_out, int out_size, void* d_ws, size_t ws_size,
                              hipStream_t stream) {
    const float* in = (const float*)d_in[0];
    int* out = (int*)d_out;
    (void)in_sizes; (void)n_in; (void)out_size; (void)d_ws; (void)ws_size;

    dim3 grid(Wn / 128, Hn, Bn);   // 2 x 192 x 2 = 768 blocks x 8 waves (3/CU)
    dim3 block(512);
    hipLaunchKernelGGL(hard_detect_kernel, grid, block, 0, stream, in, out);
}